// Round 3
// baseline (153.888 us; speedup 1.0000x reference)
//
#include <hip/hip_runtime.h>
#include <math.h>

#define VOCAB 100000
#define EMB   128
#define BATCH 16384
#define CTX   20
#define NEG   20
#define NSCORE (NEG + 1)   // target + negatives

__device__ __forceinline__ float dot4(float4 a, float4 b) {
    return fmaf(a.x, b.x, fmaf(a.y, b.y, fmaf(a.z, b.z, a.w * b.w)));
}

// softplus(x) = log(1+exp(x)) via raw v_exp_f32/v_log_f32.
// x clamped to [-10,10]; abs err ~1e-5 vs 0.29 absolute threshold.
__device__ __forceinline__ float fast_softplus(float x) {
    return __logf(1.0f + __expf(x));
}

__global__ __launch_bounds__(256, 4) void cbow_loss_kernel(
    const int*   __restrict__ pos_target,     // [B]
    const int*   __restrict__ pos_contexts,   // [B, C]
    const int*   __restrict__ pos_negatives,  // [B, N]
    const float* __restrict__ context_table,  // [VOCAB, 128]
    const float* __restrict__ output_table,   // [VOCAB, 128]
    float*       __restrict__ out)            // [1]
{
    const int tid  = threadIdx.x;
    const int lane = tid & 63;
    const int wave = tid >> 6;          // 0..3
    const int half = lane >> 5;         // 0 or 1
    const int sub  = lane & 31;         // lane within half-wave

    // one batch row per half-wave: 8 rows per 256-thread block
    const int row = blockIdx.x * 8 + wave * 2 + half;

    const float4* ctab = (const float4*)context_table;  // row stride = 32 float4
    const float4* otab = (const float4*)output_table;

    // ---- cooperative index fetch: 2 coalesced loads instead of 41
    //      broadcast loads; indices distributed via intra-32-lane shfl ----
    int cidx_l = (sub < CTX) ? pos_contexts[row * CTX + sub] : 0;
    int sidx_l = (sub < NSCORE)
                     ? (sub == 0 ? pos_target[row]
                                 : pos_negatives[row * NEG + (sub - 1)])
                     : 0;

    // ---- context sum, chunked 10-wide so ~10 gathers in flight ----
    float4 acc = make_float4(0.f, 0.f, 0.f, 0.f);
#pragma unroll
    for (int g = 0; g < 2; ++g) {
        float4 vb[10];
#pragma unroll
        for (int j = 0; j < 10; ++j) {
            const int idx = __shfl(cidx_l, g * 10 + j, 32);
            vb[j] = ctab[idx * 32 + sub];
        }
#pragma unroll
        for (int j = 0; j < 10; ++j) {
            acc.x += vb[j].x; acc.y += vb[j].y;
            acc.z += vb[j].z; acc.w += vb[j].w;
        }
    }

    // ---- per-lane partial dots for target + 20 negatives, chunked 7 ----
    float part[NSCORE];
#pragma unroll
    for (int g = 0; g < 3; ++g) {
        float4 vb[7];
#pragma unroll
        for (int j = 0; j < 7; ++j) {
            const int idx = __shfl(sidx_l, g * 7 + j, 32);
            vb[j] = otab[idx * 32 + sub];
        }
#pragma unroll
        for (int j = 0; j < 7; ++j) part[g * 7 + j] = dot4(acc, vb[j]);
    }

    // ---- 21 independent butterfly reductions (intra-half-wave) ----
#pragma unroll
    for (int s = 16; s >= 1; s >>= 1) {
#pragma unroll
        for (int n = 0; n < NSCORE; ++n) part[n] += __shfl_xor(part[n], s);
    }

    // ---- loss: softplus(-pos) + sum softplus(neg) ----
    float ps = fminf(fmaxf(part[0], -10.f), 10.f);
    float loss = fast_softplus(-ps);
#pragma unroll
    for (int n = 1; n < NSCORE; ++n) {
        float ns = fminf(fmaxf(part[n], -10.f), 10.f);
        loss += fast_softplus(ns);
    }

    // ---- block reduction: 8 half-wave results -> 1 atomic ----
    __shared__ float sdata[8];
    if (sub == 0) sdata[wave * 2 + half] = loss;
    __syncthreads();
    if (tid == 0) {
        float s = 0.f;
#pragma unroll
        for (int i = 0; i < 8; ++i) s += sdata[i];
        atomicAdd(out, s * (1.0f / (float)BATCH));
    }
}

extern "C" void kernel_launch(void* const* d_in, const int* in_sizes, int n_in,
                              void* d_out, int out_size, void* d_ws, size_t ws_size,
                              hipStream_t stream) {
    const int*   pos_target    = (const int*)d_in[0];
    const int*   pos_contexts  = (const int*)d_in[1];
    const int*   pos_negatives = (const int*)d_in[2];
    const float* context_table = (const float*)d_in[3];
    const float* output_table  = (const float*)d_in[4];
    float* out = (float*)d_out;

    // d_out is poisoned 0xAA before every timed launch; memset node is
    // graph-capturable.
    hipMemsetAsync(out, 0, sizeof(float), stream);

    const int rows_per_block = 8;  // 4 waves x 2 half-waves
    const int grid = BATCH / rows_per_block;  // 2048
    cbow_loss_kernel<<<grid, 256, 0, stream>>>(
        pos_target, pos_contexts, pos_negatives, context_table, output_table, out);
}

// Round 4
// 151.030 us; speedup vs baseline: 1.0189x; 1.0189x over previous
//
#include <hip/hip_runtime.h>
#include <math.h>

#define VOCAB 100000
#define EMB   128
#define BATCH 16384
#define CTX   20
#define NEG   20
#define NSCORE (NEG + 1)   // target + negatives

__device__ __forceinline__ float dot4(float4 a, float4 b) {
    return fmaf(a.x, b.x, fmaf(a.y, b.y, fmaf(a.z, b.z, a.w * b.w)));
}

// softplus(x) = log(1+exp(x)) via raw v_exp_f32/v_log_f32.
// x clamped to [-10,10]; abs err ~1e-5 vs 0.29 absolute threshold.
__device__ __forceinline__ float fast_softplus(float x) {
    return __logf(1.0f + __expf(x));
}

__global__ __launch_bounds__(256, 4) void cbow_loss_kernel(
    const int*   __restrict__ pos_target,     // [B]
    const int*   __restrict__ pos_contexts,   // [B, C]
    const int*   __restrict__ pos_negatives,  // [B, N]
    const float* __restrict__ context_table,  // [VOCAB, 128]
    const float* __restrict__ output_table,   // [VOCAB, 128]
    float*       __restrict__ out)            // [1]
{
    const int tid  = threadIdx.x;
    const int lane = tid & 63;
    const int wave = tid >> 6;          // 0..3
    const int q    = lane >> 4;         // quarter-wave 0..3
    const int sub  = lane & 15;         // lane within quarter

    // one batch row per quarter-wave: 16 rows per 256-thread block
    const int row = blockIdx.x * 16 + wave * 4 + q;

    const float4* ctab = (const float4*)context_table;  // row stride = 32 float4
    const float4* otab = (const float4*)output_table;

    // ---- cooperative index fetch (coalesced within each quarter) ----
    int cidx0 = pos_contexts[row * CTX + sub];                                  // ctx 0..15
    int cidx1 = (sub < CTX - 16) ? pos_contexts[row * CTX + 16 + sub] : 0;      // ctx 16..19
    int sidx0 = (sub == 0) ? pos_target[row]
                           : pos_negatives[row * NEG + sub - 1];                // score 0..15
    int sidx1 = (sub < NSCORE - 16) ? pos_negatives[row * NEG + 15 + sub] : 0;  // score 16..20

    // all-lanes-uniform (per quarter) index extraction; j is compile-time
    auto ctx_idx = [&](int j) {
        return (j < 16) ? __shfl(cidx0, j, 16) : __shfl(cidx1, j - 16, 16);
    };
    auto sc_idx = [&](int j) {
        return (j < 16) ? __shfl(sidx0, j, 16) : __shfl(sidx1, j - 16, 16);
    };

    // ================= phase 1: context sum (20 rows, chunks of 5) =========
    // lane covers 8 floats of the row: float4 at sub and at sub+16.
    float4 alo = make_float4(0.f, 0.f, 0.f, 0.f);
    float4 ahi = make_float4(0.f, 0.f, 0.f, 0.f);
    {
        float4 lo[2][5], hi[2][5];
#pragma unroll
        for (int j = 0; j < 5; ++j) {            // prologue: chunk 0
            const int idx = ctx_idx(j);
            lo[0][j] = ctab[idx * 32 + sub];
            hi[0][j] = ctab[idx * 32 + 16 + sub];
        }
#pragma unroll
        for (int g = 0; g < 4; ++g) {
            if (g + 1 < 4) {                     // prefetch chunk g+1
#pragma unroll
                for (int j = 0; j < 5; ++j) {
                    const int idx = ctx_idx((g + 1) * 5 + j);
                    lo[(g + 1) & 1][j] = ctab[idx * 32 + sub];
                    hi[(g + 1) & 1][j] = ctab[idx * 32 + 16 + sub];
                }
            }
#pragma unroll
            for (int j = 0; j < 5; ++j) {        // accumulate chunk g
                const float4 a = lo[g & 1][j], b = hi[g & 1][j];
                alo.x += a.x; alo.y += a.y; alo.z += a.z; alo.w += a.w;
                ahi.x += b.x; ahi.y += b.y; ahi.z += b.z; ahi.w += b.w;
            }
        }
    }

    // ================= phase 2: 21 score dots (chunks of 7) ================
    float part[NSCORE];
    {
        float4 slo[2][7], shi[2][7];
#pragma unroll
        for (int j = 0; j < 7; ++j) {            // prologue: chunk 0
            const int idx = sc_idx(j);
            slo[0][j] = otab[idx * 32 + sub];
            shi[0][j] = otab[idx * 32 + 16 + sub];
        }
#pragma unroll
        for (int g = 0; g < 3; ++g) {
            if (g + 1 < 3) {                     // prefetch chunk g+1
#pragma unroll
                for (int j = 0; j < 7; ++j) {
                    const int idx = sc_idx((g + 1) * 7 + j);
                    slo[(g + 1) & 1][j] = otab[idx * 32 + sub];
                    shi[(g + 1) & 1][j] = otab[idx * 32 + 16 + sub];
                }
            }
#pragma unroll
            for (int j = 0; j < 7; ++j) {
                part[g * 7 + j] =
                    dot4(alo, slo[g & 1][j]) + dot4(ahi, shi[g & 1][j]);
            }
        }
    }

    // ---- 21 independent butterfly reductions over 16 lanes (4 steps) ----
#pragma unroll
    for (int s = 8; s >= 1; s >>= 1) {
#pragma unroll
        for (int n = 0; n < NSCORE; ++n) part[n] += __shfl_xor(part[n], s);
    }

    // ---- loss: softplus(-pos) + sum softplus(neg) ----
    float ps = fminf(fmaxf(part[0], -10.f), 10.f);
    float loss = fast_softplus(-ps);
#pragma unroll
    for (int n = 1; n < NSCORE; ++n) {
        float ns = fminf(fmaxf(part[n], -10.f), 10.f);
        loss += fast_softplus(ns);
    }

    // ---- block reduction: 16 quarter-wave results -> 1 atomic ----
    __shared__ float sdata[16];
    if (sub == 0) sdata[wave * 4 + q] = loss;
    __syncthreads();
    if (tid == 0) {
        float s = 0.f;
#pragma unroll
        for (int i = 0; i < 16; ++i) s += sdata[i];
        atomicAdd(out, s * (1.0f / (float)BATCH));
    }
}

extern "C" void kernel_launch(void* const* d_in, const int* in_sizes, int n_in,
                              void* d_out, int out_size, void* d_ws, size_t ws_size,
                              hipStream_t stream) {
    const int*   pos_target    = (const int*)d_in[0];
    const int*   pos_contexts  = (const int*)d_in[1];
    const int*   pos_negatives = (const int*)d_in[2];
    const float* context_table = (const float*)d_in[3];
    const float* output_table  = (const float*)d_in[4];
    float* out = (float*)d_out;

    // d_out is poisoned 0xAA before every timed launch; memset node is
    // graph-capturable.
    hipMemsetAsync(out, 0, sizeof(float), stream);

    const int rows_per_block = 16;  // 4 waves x 4 quarter-waves
    const int grid = BATCH / rows_per_block;  // 1024
    cbow_loss_kernel<<<grid, 256, 0, stream>>>(
        pos_target, pos_contexts, pos_negatives, context_table, output_table, out);
}